// Round 4
// baseline (190.023 us; speedup 1.0000x reference)
//
#include <hip/hip_runtime.h>

#define N_NODES 256
#define F_DIM   16
#define H_DIM   2048
#define P_DIM   16
#define E_EDGES 32768

// One block per node n. Entire pipeline fused; block-local syncs only.
// out = A @ (x@W) re-associated as (A@x) @ W  (K collapses 2048 -> 16):
//   g[n][f]  = dinv[n] * sum_{e: dst=n} dinv[src] x[src][f] + dinv[n]^2 x[n][f]
//   o[n][h]  = sum_f g[n][f] W[f][h] + b[h]
//   q[n][p]  = sum_h o[n][h] Wq[n][h][p] + bq[n][p]
__global__ __launch_bounds__(256) void k_all(
    const float* __restrict__ x, const int* __restrict__ ei,
    const float* __restrict__ W, const float* __restrict__ b,
    const float* __restrict__ Wq, const float* __restrict__ bq,
    float* __restrict__ qout)
{
    __shared__ int   deg[N_NODES];
    __shared__ float dinv[N_NODES];
    __shared__ float xl[N_NODES][F_DIM];   // no pad: readers are divergent/scalar
    __shared__ float g[F_DIM];
    __shared__ float gf[F_DIM];
    __shared__ float red[4][P_DIM];

    const int n = blockIdx.x;
    const int t = threadIdx.x;
    const int* __restrict__ src = ei;
    const int* __restrict__ dst = ei + E_EDGES;

    // P0: zero histogram + g; stage x (row t = 64B, aligned float4s)
    deg[t] = 0;
    if (t < F_DIM) g[t] = 0.0f;
    {
        const float4* x4 = (const float4*)(x + t * F_DIM);
        float4 a0 = x4[0], a1 = x4[1], a2 = x4[2], a3 = x4[3];
        *(float4*)&xl[t][0]  = a0;
        *(float4*)&xl[t][4]  = a1;
        *(float4*)&xl[t][8]  = a2;
        *(float4*)&xl[t][12] = a3;
    }
    __syncthreads();

    // P1: in-degree histogram over ALL edges (redundant per block, cheap)
    for (int e = t; e < E_EDGES; e += 256)
        atomicAdd(&deg[dst[e]], 1);
    __syncthreads();

    // dinv[d] = rsqrt(deg + 1)   (+1 = self-loop)
    dinv[t] = rsqrtf((float)deg[t] + 1.0f);
    __syncthreads();

    // P2: g[f] = sum over my in-edges of dinv[src]*x[src][f]
    for (int e = t; e < E_EDGES; e += 256) {
        if (dst[e] == n) {
            int   s = src[e];
            float a = dinv[s];
#pragma unroll
            for (int f = 0; f < F_DIM; ++f)
                atomicAdd(&g[f], a * xl[s][f]);
        }
    }
    __syncthreads();
    if (t < F_DIM) {
        float dn = dinv[n];
        gf[t] = g[t] * dn + dn * dn * xl[n][t];
    }
    __syncthreads();

    float gr[F_DIM];
#pragma unroll
    for (int f = 0; f < F_DIM; ++f) gr[f] = gf[f];  // broadcast reads

    // P3: o[i] = b[hh] + sum_f gr[f]*W[f][hh]   (hh = t + 256*i)
    float o[8];
#pragma unroll
    for (int i = 0; i < 8; ++i) {
        int hh = t + 256 * i;
        float v = b[hh];
#pragma unroll
        for (int f = 0; f < F_DIM; ++f)
            v += gr[f] * W[f * H_DIM + hh];
        o[i] = v;
    }

    // P4: stream Wq[n] (128 KB), acc[p] += o * Wq[n][hh][p]
    float acc[16];
#pragma unroll
    for (int p = 0; p < 16; ++p) acc[p] = 0.0f;
    const float4* Wqn = (const float4*)(Wq + (size_t)n * H_DIM * P_DIM);
#pragma unroll
    for (int i = 0; i < 8; ++i) {
        int hh = t + 256 * i;
        float ov = o[i];
        float4 u0 = Wqn[hh * 4 + 0];
        float4 u1 = Wqn[hh * 4 + 1];
        float4 u2 = Wqn[hh * 4 + 2];
        float4 u3 = Wqn[hh * 4 + 3];
        acc[0]  += ov * u0.x; acc[1]  += ov * u0.y; acc[2]  += ov * u0.z; acc[3]  += ov * u0.w;
        acc[4]  += ov * u1.x; acc[5]  += ov * u1.y; acc[6]  += ov * u1.z; acc[7]  += ov * u1.w;
        acc[8]  += ov * u2.x; acc[9]  += ov * u2.y; acc[10] += ov * u2.z; acc[11] += ov * u2.w;
        acc[12] += ov * u3.x; acc[13] += ov * u3.y; acc[14] += ov * u3.z; acc[15] += ov * u3.w;
    }

    // wave butterfly reduce (64 lanes), then cross-wave via LDS
#pragma unroll
    for (int p = 0; p < 16; ++p)
#pragma unroll
        for (int off = 32; off > 0; off >>= 1)
            acc[p] += __shfl_down(acc[p], off, 64);

    int wave = t >> 6, lane = t & 63;
    if (lane == 0) {
#pragma unroll
        for (int p = 0; p < 16; ++p) red[wave][p] = acc[p];
    }
    __syncthreads();
    if (t < P_DIM) {
        float s = red[0][t] + red[1][t] + red[2][t] + red[3][t] +
                  bq[n * P_DIM + t];
        qout[n * P_DIM + t] = s;
    }
}

extern "C" void kernel_launch(void* const* d_in, const int* in_sizes, int n_in,
                              void* d_out, int out_size, void* d_ws, size_t ws_size,
                              hipStream_t stream) {
    const float* x  = (const float*)d_in[0];  // [256,16]
    const int*   ei = (const int*)d_in[1];    // [2,32768] (int32 on device)
    const float* W  = (const float*)d_in[2];  // [16,2048]
    const float* b  = (const float*)d_in[3];  // [2048]
    const float* Wq = (const float*)d_in[4];  // [256,2048,16]
    const float* bq = (const float*)d_in[5];  // [256,16]
    float* qout = (float*)d_out;              // [256,16]

    k_all<<<N_NODES, 256, 0, stream>>>(x, ei, W, b, Wq, bq, qout);
}

// Round 5
// 109.626 us; speedup vs baseline: 1.7334x; 1.7334x over previous
//
#include <hip/hip_runtime.h>

#define N_NODES 256
#define F_DIM   16
#define H_DIM   2048
#define P_DIM   16
#define E_EDGES 32768

// ---------------------------------------------------------------------------
// Algebra: out = A@(x@W)+b re-associated as (A@x)@W+b (K: 2048 -> 16), with
//   A[d][s] = dinv[d]*dinv[s]*count(s->d), self-loop = extra edge n->n.
//   g[n][f] = dinv[n] * sum_s (cnt[s][n] + [s==n]) * dinv[s] * x[s][f]
//   o[n][h] = sum_f g[n][f] W[f][h] + b[h];  q[n][p] = sum_h o[n][h] Wq[n][h][p] + bq[n][p]
// ws: cntT[65536] floats, cntT[s*256+d].
// ---------------------------------------------------------------------------

// K1: edge-parallel count build. 65536 addresses, ~0.5 edges each -> low contention.
__global__ __launch_bounds__(256) void k_cnt(const int* __restrict__ ei,
                                             float* __restrict__ cntT) {
    int e = blockIdx.x * 256 + threadIdx.x;     // covers 32768 exactly
    int s = ei[e];
    int d = ei[E_EDGES + e];
    atomicAdd(&cntT[s * N_NODES + d], 1.0f);
}

// K2: one block per node. colsum(cntT)->dinv (coalesced), own g row, o regs, Wq stream.
__global__ __launch_bounds__(256) void k_node(
    const float* __restrict__ cntT, const float* __restrict__ x,
    const float* __restrict__ W, const float* __restrict__ b,
    const float* __restrict__ Wq, const float* __restrict__ bq,
    float* __restrict__ qout)
{
    __shared__ float part[4][256];      // colsum partials per wave
    __shared__ float dinv[N_NODES];
    __shared__ float xlT[F_DIM][N_NODES];  // transposed: stores & reads conflict-free
    __shared__ float g[F_DIM];
    __shared__ float red[4][P_DIM];

    const int n = blockIdx.x;
    const int t = threadIdx.x;
    const int w = t >> 6, l = t & 63;

    if (t < F_DIM) g[t] = 0.0f;

    // stage x transposed: thread t owns node-row t (64B float4 loads, scatter to LDS)
    {
        const float4* x4 = (const float4*)(x + t * F_DIM);
        float4 a0 = x4[0], a1 = x4[1], a2 = x4[2], a3 = x4[3];
        xlT[0][t]  = a0.x; xlT[1][t]  = a0.y; xlT[2][t]  = a0.z; xlT[3][t]  = a0.w;
        xlT[4][t]  = a1.x; xlT[5][t]  = a1.y; xlT[6][t]  = a1.z; xlT[7][t]  = a1.w;
        xlT[8][t]  = a2.x; xlT[9][t]  = a2.y; xlT[10][t] = a2.z; xlT[11][t] = a2.w;
        xlT[12][t] = a3.x; xlT[13][t] = a3.y; xlT[14][t] = a3.z; xlT[15][t] = a3.w;
    }

    // colsum of cntT (deg[d] = sum_s cntT[s][d]): wave w sums s in [64w, 64w+64),
    // lane l owns cols 4l..4l+3 — fully coalesced float4 loads, 64-deep ILP.
    {
        const float4* cT4 = (const float4*)cntT;   // row s = 64 float4
        float4 sum = {0.f, 0.f, 0.f, 0.f};
        int s0 = w * 64;
#pragma unroll 16
        for (int s = s0; s < s0 + 64; ++s) {
            float4 v = cT4[s * 64 + l];
            sum.x += v.x; sum.y += v.y; sum.z += v.z; sum.w += v.w;
        }
        *(float4*)&part[w][4 * l] = sum;
    }
    __syncthreads();

    if (t < 64) {
        float4 a0 = *(float4*)&part[0][4 * t];
        float4 a1 = *(float4*)&part[1][4 * t];
        float4 a2 = *(float4*)&part[2][4 * t];
        float4 a3 = *(float4*)&part[3][4 * t];
        dinv[4 * t + 0] = rsqrtf(a0.x + a1.x + a2.x + a3.x + 1.0f);
        dinv[4 * t + 1] = rsqrtf(a0.y + a1.y + a2.y + a3.y + 1.0f);
        dinv[4 * t + 2] = rsqrtf(a0.z + a1.z + a2.z + a3.z + 1.0f);
        dinv[4 * t + 3] = rsqrtf(a0.w + a1.w + a2.w + a3.w + 1.0f);
    }
    __syncthreads();

    // own g row: thread t handles source s=t; self-loop folds as cnt[n][n]+1
    {
        float a = cntT[t * N_NODES + n] + (t == n ? 1.0f : 0.0f);
        a *= dinv[t];
        if (a != 0.0f) {
#pragma unroll
            for (int f = 0; f < F_DIM; ++f)
                atomicAdd(&g[f], a * xlT[f][t]);
        }
    }
    __syncthreads();

    float dn = dinv[n];
    float gr[F_DIM];
#pragma unroll
    for (int f = 0; f < F_DIM; ++f) gr[f] = g[f] * dn;   // LDS broadcast reads

    // o[i] = b[hh] + sum_f gr[f]*W[f][hh],  hh = t + 256*i  (coalesced)
    float o[8];
#pragma unroll
    for (int i = 0; i < 8; ++i) {
        int hh = t + 256 * i;
        float v = b[hh];
#pragma unroll
        for (int f = 0; f < F_DIM; ++f)
            v += gr[f] * W[f * H_DIM + hh];
        o[i] = v;
    }

    // stream Wq[n] (128 KB/block, coalesced float4): acc[p] += o*Wq[n][hh][p]
    float acc[16];
#pragma unroll
    for (int p = 0; p < 16; ++p) acc[p] = 0.0f;
    const float4* Wqn = (const float4*)(Wq + (size_t)n * H_DIM * P_DIM);
#pragma unroll
    for (int i = 0; i < 8; ++i) {
        int hh = t + 256 * i;
        float ov = o[i];
        float4 u0 = Wqn[hh * 4 + 0];
        float4 u1 = Wqn[hh * 4 + 1];
        float4 u2 = Wqn[hh * 4 + 2];
        float4 u3 = Wqn[hh * 4 + 3];
        acc[0]  += ov * u0.x; acc[1]  += ov * u0.y; acc[2]  += ov * u0.z; acc[3]  += ov * u0.w;
        acc[4]  += ov * u1.x; acc[5]  += ov * u1.y; acc[6]  += ov * u1.z; acc[7]  += ov * u1.w;
        acc[8]  += ov * u2.x; acc[9]  += ov * u2.y; acc[10] += ov * u2.z; acc[11] += ov * u2.w;
        acc[12] += ov * u3.x; acc[13] += ov * u3.y; acc[14] += ov * u3.z; acc[15] += ov * u3.w;
    }

    // wave butterfly (64 lanes) then cross-wave via LDS
#pragma unroll
    for (int p = 0; p < 16; ++p)
#pragma unroll
        for (int off = 32; off > 0; off >>= 1)
            acc[p] += __shfl_down(acc[p], off, 64);

    if (l == 0) {
#pragma unroll
        for (int p = 0; p < 16; ++p) red[w][p] = acc[p];
    }
    __syncthreads();
    if (t < P_DIM) {
        float s = red[0][t] + red[1][t] + red[2][t] + red[3][t] +
                  bq[n * P_DIM + t];
        qout[n * P_DIM + t] = s;
    }
}

extern "C" void kernel_launch(void* const* d_in, const int* in_sizes, int n_in,
                              void* d_out, int out_size, void* d_ws, size_t ws_size,
                              hipStream_t stream) {
    const float* x  = (const float*)d_in[0];  // [256,16]
    const int*   ei = (const int*)d_in[1];    // [2,32768]
    const float* W  = (const float*)d_in[2];  // [16,2048]
    const float* b  = (const float*)d_in[3];  // [2048]
    const float* Wq = (const float*)d_in[4];  // [256,2048,16]
    const float* bq = (const float*)d_in[5];  // [256,16]
    float* qout = (float*)d_out;              // [256,16]

    float* cntT = (float*)d_ws;               // 65536 floats (256 KB)

    hipMemsetAsync(cntT, 0, N_NODES * N_NODES * sizeof(float), stream);
    k_cnt <<<128, 256, 0, stream>>>(ei, cntT);
    k_node<<<N_NODES, 256, 0, stream>>>(cntT, x, W, b, Wq, bq, qout);
}